// Round 3
// baseline (185.573 us; speedup 1.0000x reference)
//
#include <hip/hip_runtime.h>

// LogSumExpPooling2D: x (8,256,256,64) f32 NHWC ->
// out (1,128,128,64): (1/100)*logsumexp(100*x) over 2x2 stride-2 window AND batch.
// Memory-bound: 134 MB read + 4 MB write, ~21 us HBM floor @ 6.3-6.9 TB/s.
//
// R3: fully-contiguous wave loads. A wave owns 8 input pixel-columns of one
// row-pair; per (n,dh) it issues two contiguous 1-KiB loads (lane i -> byte
// 16*i). Each lane holds online-lse state for 2 columns; the dw-pair merge is
// a single __shfl_xor(16) at the end; half-wave float4 stores for output.
// (R1/R2 wave-loads were 4x 256-B segments @ stride 512 — suspected culprit.)

constexpr float SCALE = 100.0f;
constexpr float INV_SCALE = 0.01f;

__device__ inline void chunk_merge(const float4& v0, const float4& v1,
                                   float m[4], float s[4]) {
    const float e0[4] = {v0.x, v0.y, v0.z, v0.w};
    const float e1[4] = {v1.x, v1.y, v1.z, v1.w};
#pragma unroll
    for (int j = 0; j < 4; ++j) {
        const float cm = fmaxf(e0[j], e1[j]);
        const float cs = __expf((e0[j] - cm) * SCALE) + __expf((e1[j] - cm) * SCALE);
        const float mn = fmaxf(m[j], cm);
        s[j] = s[j] * __expf((m[j] - mn) * SCALE) + cs * __expf((cm - mn) * SCALE);
        m[j] = mn;
    }
}

__global__ __launch_bounds__(256) void lse_pool_kernel(const float* __restrict__ x,
                                                       float* __restrict__ out) {
    const int tid = blockIdx.x * 256 + threadIdx.x;
    const int l   = tid & 63;        // lane
    const int wv  = tid >> 6;        // global wave 0..4095
    const int ho  = wv >> 5;         // output row 0..127
    const int p0  = (wv & 31) << 3;  // input pixel-column base: 0,8,...,248

    const size_t NS = (size_t)256 * 256 * 64;  // batch stride (floats)
    const size_t HS = (size_t)256 * 64;        // row stride (floats)
    // (n=0, h=2*ho, pixel p0, lane's 16B slice). Lane l covers pixel p0+(l>>4),
    // channels 4*(l&15)..+3; the wave's 64 lanes are one contiguous 1 KiB.
    const float* base = x + (((size_t)(2 * ho) * 256) + (size_t)p0) * 64 + (size_t)(l * 4);

    // Online state: colA = pixel p0+(l>>4), colB = pixel p0+4+(l>>4).
    float mA[4], sA[4], mB[4], sB[4];
#pragma unroll
    for (int j = 0; j < 4; ++j) { mA[j] = -1e30f; sA[j] = 0.f; mB[j] = -1e30f; sB[j] = 0.f; }

#pragma unroll 2
    for (int n = 0; n < 8; ++n) {
        const float* pn = base + (size_t)n * NS;
        const float4 a0 = *reinterpret_cast<const float4*>(pn);            // dh=0, cols 0-3
        const float4 b0 = *reinterpret_cast<const float4*>(pn + 256);      // dh=0, cols 4-7
        const float4 a1 = *reinterpret_cast<const float4*>(pn + HS);       // dh=1, cols 0-3
        const float4 b1 = *reinterpret_cast<const float4*>(pn + HS + 256); // dh=1, cols 4-7
        chunk_merge(a0, a1, mA, sA);
        chunk_merge(b0, b1, mB, sB);
    }

    // dw-pair merge: lanes l and l^16 hold adjacent pixel columns.
#pragma unroll
    for (int j = 0; j < 4; ++j) {
        {
            const float m2 = __shfl_xor(mA[j], 16);
            const float s2 = __shfl_xor(sA[j], 16);
            const float mn = fmaxf(mA[j], m2);
            sA[j] = sA[j] * __expf((mA[j] - mn) * SCALE) + s2 * __expf((m2 - mn) * SCALE);
            mA[j] = mn;
        }
        {
            const float m2 = __shfl_xor(mB[j], 16);
            const float s2 = __shfl_xor(sB[j], 16);
            const float mn = fmaxf(mB[j], m2);
            sB[j] = sB[j] * __expf((mB[j] - mn) * SCALE) + s2 * __expf((m2 - mn) * SCALE);
            mB[j] = mn;
        }
    }

    if ((l & 16) == 0) {  // lanes with q = l>>4 in {0,2} hold the merged pairs
        float4 rA, rB;
        rA.x = mA[0] + __logf(sA[0]) * INV_SCALE;
        rA.y = mA[1] + __logf(sA[1]) * INV_SCALE;
        rA.z = mA[2] + __logf(sA[2]) * INV_SCALE;
        rA.w = mA[3] + __logf(sA[3]) * INV_SCALE;
        rB.x = mB[0] + __logf(sB[0]) * INV_SCALE;
        rB.y = mB[1] + __logf(sB[1]) * INV_SCALE;
        rB.z = mB[2] + __logf(sB[2]) * INV_SCALE;
        rB.w = mB[3] + __logf(sB[3]) * INV_SCALE;

        const int c  = (l & 15) << 2;
        const int wo = (p0 >> 1) + (l >> 5);            // colA output pixel
        const size_t o = ((size_t)ho * 128 + (size_t)wo) * 64 + (size_t)c;
        *reinterpret_cast<float4*>(out + o)            = rA;  // wo
        *reinterpret_cast<float4*>(out + o + 2 * 64)   = rB;  // wo + 2
    }
}

extern "C" void kernel_launch(void* const* d_in, const int* in_sizes, int n_in,
                              void* d_out, int out_size, void* d_ws, size_t ws_size,
                              hipStream_t stream) {
    const float* x = (const float*)d_in[0];
    float* out = (float*)d_out;
    // 4096 waves (128 row-pairs x 32 column-groups) = 1024 blocks of 256
    lse_pool_kernel<<<1024, 256, 0, stream>>>(x, out);
}